// Round 4
// baseline (782.818 us; speedup 1.0000x reference)
//
#include <hip/hip_runtime.h>

// TopicRouter: logits = h @ gate_w^T + gate_b ; top-2 ; softmax over top-2.
// Outputs flat in d_out (float32): [0, 2B)   = topk indices as floats
//                                  [2B, 4B)  = softmax weights
//
// R4 design (from R3 counters: latency-bound — VALUBusy 25.6%, HBM 10.8%,
// occupancy 21%):
//  - wave-per-token, lane owns dims {g*256 + lane*4 + j}; gate_w cached in
//    96 f32 VGPRs/lane; f64 accumulation (a single top-2 rank flip vs the
//    f64 np ref fails the 0.14 idx threshold; f32 dot error ~1e-6 vs
//    expected min rank2/rank3 gap ~4e-6 over 131072 tokens).
//  - NEW: split-butterfly reduce — xor32/16/8 levels exchange expert
//    halves (each lane ends owning one expert), then xor4/2/1 pure
//    reduce, then 8-wide gather. 36 b32 DS ops/token vs 96 before.
//  - NEW: one-token-ahead prefetch (nbuf) so the ~900-cyc HBM latency
//    hides under the ~800-cyc/token compute.
//  - bias kept as f32 in SGPRs (uniform load), converted to f64 per use:
//    saves 16 VGPRs; __launch_bounds__(256,3) caps VGPR ~170 -> 3 waves/SIMD.
//  - grid = 768 blocks = exactly 3 blocks/CU resident; grid-stride ~43
//    tokens/wave amortizes the wf load (gw is 24 KB -> L2-resident).

#define B_TOKENS 131072
#define DM 768
#define NE 8

__global__ __launch_bounds__(256, 3) void topic_router_kernel(
    const float* __restrict__ h,     // [B, 768]
    const float* __restrict__ gw,    // [8, 768]
    const float* __restrict__ gb,    // [8]
    float* __restrict__ out)         // [2B idx floats][2B weight floats]
{
    const int lane = threadIdx.x & 63;
    const int wid = (blockIdx.x * blockDim.x + threadIdx.x) >> 6;
    const int n_waves = (gridDim.x * blockDim.x) >> 6;

    // Cache gate_w fragments: wf[e][g][j] = gw[e][g*256 + lane*4 + j]
    float wf[NE][3][4];
#pragma unroll
    for (int e = 0; e < NE; ++e)
#pragma unroll
        for (int g = 0; g < 3; ++g) {
            const float4 v = *reinterpret_cast<const float4*>(
                &gw[e * DM + g * 256 + lane * 4]);
            wf[e][g][0] = v.x; wf[e][g][1] = v.y;
            wf[e][g][2] = v.z; wf[e][g][3] = v.w;
        }

    // Uniform loads -> SGPRs; converted to f64 at use (8 cvt/token).
    float biasf[NE];
#pragma unroll
    for (int e = 0; e < NE; ++e) biasf[e] = gb[e];

    const bool hi32 = (lane & 32) != 0;
    const bool hi16 = (lane & 16) != 0;
    const bool hi8  = (lane & 8)  != 0;

    int t = wid;
    float4 buf[3];
    if (t < B_TOKENS) {
        const float* hr = h + (size_t)t * DM;
#pragma unroll
        for (int g = 0; g < 3; ++g)
            buf[g] = *reinterpret_cast<const float4*>(&hr[g * 256 + lane * 4]);
    }

    for (; t < B_TOKENS; t += n_waves) {
        // ---- prefetch next token's row (stays in flight during compute) ----
        float4 nbuf[3];
        const int tn = t + n_waves;
        if (tn < B_TOKENS) {
            const float* hr = h + (size_t)tn * DM;
#pragma unroll
            for (int g = 0; g < 3; ++g)
                nbuf[g] = *reinterpret_cast<const float4*>(&hr[g * 256 + lane * 4]);
        }

        // ---- f64 partial dot: 96 FMAs/lane (12 dims x 8 experts) ----
        double acc[NE] = {0, 0, 0, 0, 0, 0, 0, 0};
#pragma unroll
        for (int g = 0; g < 3; ++g) {
            const float* bp = reinterpret_cast<const float*>(&buf[g]);
#pragma unroll
            for (int j = 0; j < 4; ++j) {
                const double hd = (double)bp[j];
#pragma unroll
                for (int e = 0; e < NE; ++e)
                    acc[e] = fma(hd, (double)wf[e][g][j], acc[e]);
            }
        }

        // ---- split-butterfly reduce ----
        // L1 (xor 32): keep experts (hi32 ? 4..7 : 0..3); give away the rest.
        double r4[4];
#pragma unroll
        for (int j = 0; j < 4; ++j) {
            const double give = hi32 ? acc[j] : acc[4 + j];
            const double keep = hi32 ? acc[4 + j] : acc[j];
            r4[j] = keep + __shfl_xor(give, 32);
        }
        // L2 (xor 16): keep (hi16 ? {2,3} : {0,1}) of the current 4.
        double r2[2];
#pragma unroll
        for (int j = 0; j < 2; ++j) {
            const double give = hi16 ? r4[j] : r4[2 + j];
            const double keep = hi16 ? r4[2 + j] : r4[j];
            r2[j] = keep + __shfl_xor(give, 16);
        }
        // L3 (xor 8): keep (hi8 ? [1] : [0]).
        {
            const double give = hi8 ? r2[0] : r2[1];
            const double keep = hi8 ? r2[1] : r2[0];
            double v = keep + __shfl_xor(give, 8);
            // lane now owns expert e = (lane>>3)&7; finish the 8-lane reduce
            v += __shfl_xor(v, 4);
            v += __shfl_xor(v, 2);
            v += __shfl_xor(v, 1);

            // ---- gather all 8 expert logits into every lane, add bias ----
            double lg[NE];
#pragma unroll
            for (int e = 0; e < NE; ++e)
                lg[e] = __shfl(v, (e << 3) | (lane & 7)) + (double)biasf[e];

            // ---- top-2, lax.top_k tie-break (lower index wins) ----
            int i0 = 0; double v0 = lg[0];
#pragma unroll
            for (int e = 1; e < NE; ++e)
                if (lg[e] > v0) { v0 = lg[e]; i0 = e; }
            int i1 = (i0 == 0) ? 1 : 0; double v1 = lg[i1];
#pragma unroll
            for (int e = 0; e < NE; ++e)
                if (e != i0 && lg[e] > v1) { v1 = lg[e]; i1 = e; }

            // softmax over [v0, v1], v0 >= v1
            const float ex = expf((float)(v1 - v0));   // in (0, 1]
            const float w1 = ex / (1.0f + ex);
            const float w0 = 1.0f - w1;

            if (lane == 0) {
                *reinterpret_cast<float2*>(&out[2 * (size_t)t]) =
                    make_float2((float)i0, (float)i1);
                *reinterpret_cast<float2*>(
                    &out[2 * (size_t)B_TOKENS + 2 * (size_t)t]) =
                    make_float2(w0, w1);
            }
        }

        // rotate prefetch buffer
#pragma unroll
        for (int g = 0; g < 3; ++g) buf[g] = nbuf[g];
    }
}

extern "C" void kernel_launch(void* const* d_in, const int* in_sizes, int n_in,
                              void* d_out, int out_size, void* d_ws, size_t ws_size,
                              hipStream_t stream) {
    const float* h  = (const float*)d_in[0];
    const float* gw = (const float*)d_in[1];
    const float* gb = (const float*)d_in[2];
    float* out = (float*)d_out;

    dim3 grid(768), block(256);   // 3 blocks/CU resident at 3 waves/SIMD
    topic_router_kernel<<<grid, block, 0, stream>>>(h, gw, gb, out);
}

// Round 5
// 658.766 us; speedup vs baseline: 1.1883x; 1.1883x over previous
//
#include <hip/hip_runtime.h>

// TopicRouter: logits = h @ gate_w^T + gate_b ; top-2 ; softmax over top-2.
// Outputs flat in d_out (float32): [0, 2B)   = topk indices as floats
//                                  [2B, 4B)  = softmax weights
//
// R5 design — thread-per-token (from R3/R4 post-mortems):
//  * R3 (wave-per-token): latency-bound, 96 DS-shuffle ops/token serial chain.
//  * R4 (launch_bounds(256,3)): VGPR=84 -> weight cache spilled, FETCH 1.81 GB.
//  * Fix: thread owns a whole token; 8 f64 accumulators in-register ->
//    the 768-dim reduction has ZERO cross-lane ops. gate_w in LDS (24 KB,
//    broadcast float4 reads = conflict-free). h staged in LDS chunks of
//    32 dims, pad stride 36 words -> uniform 8 words/bank on ds_read_b128
//    (conflict-free). 2-deep register prefetch so HBM stays saturated
//    across the per-chunk barriers.
//  * f64 accumulation kept: idx output threshold 0.14 means one top-2 rank
//    flip vs the f64 np ref fails; f32 dot error ~1e-6 vs expected min
//    rank2/rank3 gap ~4e-6 over 131072 tokens.
//  * 512 blocks x 256 threads = exact token cover; 60 KB LDS -> 2 blocks/CU.

#define B_TOKENS 131072
#define DM 768
#define NE 8
#define TPB 256        // threads per block == tokens per block
#define CHUNK 32       // dims per chunk
#define NCH 24         // 768 / 32
#define PADW 36        // padded LDS row stride (words); 36%32=4 -> conflict-free b128

__global__ __launch_bounds__(256) void topic_router_kernel(
    const float* __restrict__ h,     // [B, 768]
    const float* __restrict__ gw,    // [8, 768]
    const float* __restrict__ gb,    // [8]
    float* __restrict__ out)         // [2B idx floats][2B weight floats]
{
    __shared__ __align__(16) float w_lds[NE * DM];      // 24 KB
    __shared__ __align__(16) float h_lds[TPB * PADW];   // 36 KB

    const int tid = threadIdx.x;
    const int tb  = blockIdx.x * TPB;
    const int c4  = tid & 7;   // float4-column within chunk
    const int r0  = tid >> 3;  // base row; rows r0 + 32*s, s=0..7

    // ---- issue gate_w loads: 6144 f32 = 1536 float4, 6 per thread ----
    float4 wr[6];
#pragma unroll
    for (int s = 0; s < 6; ++s)
        wr[s] = *reinterpret_cast<const float4*>(&gw[(tid + s * TPB) * 4]);

    // ---- issue chunk0 -> A, chunk1 -> B (coalesced: 8 full 128B lines/wave/instr) ----
    float4 A[8], Bf[8];
#pragma unroll
    for (int s = 0; s < 8; ++s)
        A[s] = *reinterpret_cast<const float4*>(
            &h[(size_t)(tb + r0 + 32 * s) * DM + 0 * CHUNK + c4 * 4]);
#pragma unroll
    for (int s = 0; s < 8; ++s)
        Bf[s] = *reinterpret_cast<const float4*>(
            &h[(size_t)(tb + r0 + 32 * s) * DM + 1 * CHUNK + c4 * 4]);

    // ---- stage w + chunk0 into LDS ----
#pragma unroll
    for (int s = 0; s < 6; ++s)
        *reinterpret_cast<float4*>(&w_lds[(tid + s * TPB) * 4]) = wr[s];
#pragma unroll
    for (int s = 0; s < 8; ++s)
        *reinterpret_cast<float4*>(&h_lds[(r0 + 32 * s) * PADW + c4 * 4]) = A[s];
    __syncthreads();

    double acc[NE] = {0, 0, 0, 0, 0, 0, 0, 0};

#define LOADC(R, K)                                                          \
    _Pragma("unroll")                                                        \
    for (int s = 0; s < 8; ++s)                                              \
        R[s] = *reinterpret_cast<const float4*>(                             \
            &h[(size_t)(tb + r0 + 32 * s) * DM + (K) * CHUNK + c4 * 4]);

#define WRITEC(R)                                                            \
    _Pragma("unroll")                                                        \
    for (int s = 0; s < 8; ++s)                                              \
        *reinterpret_cast<float4*>(                                          \
            &h_lds[(r0 + 32 * s) * PADW + c4 * 4]) = R[s];

#define COMPUTE(K)                                                           \
    {                                                                        \
        const float* hrow = &h_lds[tid * PADW];                              \
        _Pragma("unroll")                                                    \
        for (int j = 0; j < 8; ++j) {                                        \
            const float4 h4 = *reinterpret_cast<const float4*>(&hrow[j*4]);  \
            const double hd0 = (double)h4.x, hd1 = (double)h4.y;             \
            const double hd2 = (double)h4.z, hd3 = (double)h4.w;             \
            _Pragma("unroll")                                                \
            for (int e = 0; e < NE; ++e) {                                   \
                const float4 w4 = *reinterpret_cast<const float4*>(          \
                    &w_lds[e * DM + (K) * CHUNK + j * 4]);                   \
                acc[e] = fma(hd0, (double)w4.x, acc[e]);                     \
                acc[e] = fma(hd1, (double)w4.y, acc[e]);                     \
                acc[e] = fma(hd2, (double)w4.z, acc[e]);                     \
                acc[e] = fma(hd3, (double)w4.w, acc[e]);                     \
            }                                                                \
        }                                                                    \
    }

    // Steady state: LDS holds chunk k; regs B hold chunk k+1 (in flight or
    // arrived); issue k+2 into A before computing k. Named A/B (no runtime
    // indexing -> no scratch, rule #20), loop unrolled by 2.
    for (int k = 0; k < NCH; k += 2) {
        if (k + 2 < NCH) { LOADC(A, k + 2); }
        COMPUTE(k);
        __syncthreads();
        WRITEC(Bf);                    // chunk k+1 -> LDS
        __syncthreads();
        if (k + 3 < NCH) { LOADC(Bf, k + 3); }
        COMPUTE(k + 1);
        __syncthreads();
        if (k + 2 < NCH) {
            WRITEC(A);                 // chunk k+2 -> LDS
            __syncthreads();
        }
    }

    // ---- epilogue: bias, top-2 (lax.top_k tie-break: lower index), softmax ----
    double lg[NE];
#pragma unroll
    for (int e = 0; e < NE; ++e) lg[e] = acc[e] + (double)gb[e];

    int i0 = 0; double v0 = lg[0];
#pragma unroll
    for (int e = 1; e < NE; ++e)
        if (lg[e] > v0) { v0 = lg[e]; i0 = e; }
    int i1 = (i0 == 0) ? 1 : 0; double v1 = lg[i1];
#pragma unroll
    for (int e = 0; e < NE; ++e)
        if (e != i0 && lg[e] > v1) { v1 = lg[e]; i1 = e; }

    const float ex = expf((float)(v1 - v0));   // in (0, 1]
    const float w1 = ex / (1.0f + ex);
    const float w0 = 1.0f - w1;

    const size_t t = (size_t)(tb + tid);
    *reinterpret_cast<float2*>(&out[2 * t]) = make_float2((float)i0, (float)i1);
    *reinterpret_cast<float2*>(&out[2 * (size_t)B_TOKENS + 2 * t]) =
        make_float2(w0, w1);
}

extern "C" void kernel_launch(void* const* d_in, const int* in_sizes, int n_in,
                              void* d_out, int out_size, void* d_ws, size_t ws_size,
                              hipStream_t stream) {
    const float* h  = (const float*)d_in[0];
    const float* gw = (const float*)d_in[1];
    const float* gb = (const float*)d_in[2];
    float* out = (float*)d_out;

    dim3 grid(B_TOKENS / TPB), block(TPB);   // 512 blocks, exact cover
    topic_router_kernel<<<grid, block, 0, stream>>>(h, gw, gb, out);
}

// Round 6
// 203.104 us; speedup vs baseline: 3.8543x; 3.2435x over previous
//
#include <hip/hip_runtime.h>

// TopicRouter: logits = h @ gate_w^T + gate_b ; top-2 ; softmax over top-2.
// Outputs flat in d_out (float32): [0, 2B)   = topk indices as floats
//                                  [2B, 4B)  = softmax weights
//
// R6 = R4 logic (verified correct) with the two spill-inducing choices fixed:
//  * NO min-waves launch bound (R4's (256,3) forced VGPR=84 -> the 96-VGPR
//    weight cache spilled -> FETCH 1.77 GB, 804 us).
//  * grid 2048 (R3's) for parallelism; grid-stride 16 tokens/wave amortizes
//    the wf load; gw re-reads are L2-resident.
// Design: wave-per-token; lane owns dims {g*256 + lane*4 + j}; gate_w cached
// in 96 f32 VGPRs/lane; f64 accumulation (one top-2 rank flip vs the f64 np
// ref fails the 0.14 idx threshold; f32 dot error ~1e-6 vs expected min
// rank2/rank3 gap ~4e-6 over 131072 tokens). Split-butterfly reduce:
// xor32/16/8 exchange expert halves (36 DS-b32 ops/token vs 96 naive), then
// xor4/2/1 pure reduce + 8-wide gather. One-token-ahead register prefetch
// hides the ~900-cyc HBM latency under the ~950-cyc/token VALU work.

#define B_TOKENS 131072
#define DM 768
#define NE 8

__global__ __launch_bounds__(256) void topic_router_kernel(
    const float* __restrict__ h,     // [B, 768]
    const float* __restrict__ gw,    // [8, 768]
    const float* __restrict__ gb,    // [8]
    float* __restrict__ out)         // [2B idx floats][2B weight floats]
{
    const int lane = threadIdx.x & 63;
    const int wid = (blockIdx.x * blockDim.x + threadIdx.x) >> 6;
    const int n_waves = (gridDim.x * blockDim.x) >> 6;

    // Cache gate_w fragments: wf[e][g][j] = gw[e][g*256 + lane*4 + j]
    float wf[NE][3][4];
#pragma unroll
    for (int e = 0; e < NE; ++e)
#pragma unroll
        for (int g = 0; g < 3; ++g) {
            const float4 v = *reinterpret_cast<const float4*>(
                &gw[e * DM + g * 256 + lane * 4]);
            wf[e][g][0] = v.x; wf[e][g][1] = v.y;
            wf[e][g][2] = v.z; wf[e][g][3] = v.w;
        }

    float biasf[NE];
#pragma unroll
    for (int e = 0; e < NE; ++e) biasf[e] = gb[e];

    const bool hi32 = (lane & 32) != 0;
    const bool hi16 = (lane & 16) != 0;
    const bool hi8  = (lane & 8)  != 0;

    int t = wid;
    float4 buf[3];
    if (t < B_TOKENS) {
        const float* hr = h + (size_t)t * DM;
#pragma unroll
        for (int g = 0; g < 3; ++g)
            buf[g] = *reinterpret_cast<const float4*>(&hr[g * 256 + lane * 4]);
    }

    for (; t < B_TOKENS; t += n_waves) {
        // ---- prefetch next token's row (stays in flight during compute) ----
        float4 nbuf[3];
        const int tn = t + n_waves;
        if (tn < B_TOKENS) {
            const float* hr = h + (size_t)tn * DM;
#pragma unroll
            for (int g = 0; g < 3; ++g)
                nbuf[g] = *reinterpret_cast<const float4*>(&hr[g * 256 + lane * 4]);
        }

        // ---- f64 partial dot: 96 FMAs/lane (12 dims x 8 experts) ----
        double acc[NE] = {0, 0, 0, 0, 0, 0, 0, 0};
#pragma unroll
        for (int g = 0; g < 3; ++g) {
            const float* bp = reinterpret_cast<const float*>(&buf[g]);
#pragma unroll
            for (int j = 0; j < 4; ++j) {
                const double hd = (double)bp[j];
#pragma unroll
                for (int e = 0; e < NE; ++e)
                    acc[e] = fma(hd, (double)wf[e][g][j], acc[e]);
            }
        }

        // ---- split-butterfly reduce ----
        // L1 (xor 32): keep experts (hi32 ? 4..7 : 0..3); give away the rest.
        double r4[4];
#pragma unroll
        for (int j = 0; j < 4; ++j) {
            const double give = hi32 ? acc[j] : acc[4 + j];
            const double keep = hi32 ? acc[4 + j] : acc[j];
            r4[j] = keep + __shfl_xor(give, 32);
        }
        // L2 (xor 16): keep (hi16 ? {2,3} : {0,1}) of the current 4.
        double r2[2];
#pragma unroll
        for (int j = 0; j < 2; ++j) {
            const double give = hi16 ? r4[j] : r4[2 + j];
            const double keep = hi16 ? r4[2 + j] : r4[j];
            r2[j] = keep + __shfl_xor(give, 16);
        }
        // L3 (xor 8): keep (hi8 ? [1] : [0]).
        {
            const double give = hi8 ? r2[0] : r2[1];
            const double keep = hi8 ? r2[1] : r2[0];
            double v = keep + __shfl_xor(give, 8);
            // lane now owns expert e = (lane>>3)&7; finish the 8-lane reduce
            v += __shfl_xor(v, 4);
            v += __shfl_xor(v, 2);
            v += __shfl_xor(v, 1);

            // ---- gather all 8 expert logits into every lane, add bias ----
            double lg[NE];
#pragma unroll
            for (int e = 0; e < NE; ++e)
                lg[e] = __shfl(v, (e << 3) | (lane & 7)) + (double)biasf[e];

            // ---- top-2, lax.top_k tie-break (lower index wins) ----
            int i0 = 0; double v0 = lg[0];
#pragma unroll
            for (int e = 1; e < NE; ++e)
                if (lg[e] > v0) { v0 = lg[e]; i0 = e; }
            int i1 = (i0 == 0) ? 1 : 0; double v1 = lg[i1];
#pragma unroll
            for (int e = 0; e < NE; ++e)
                if (e != i0 && lg[e] > v1) { v1 = lg[e]; i1 = e; }

            // softmax over [v0, v1], v0 >= v1
            const float ex = expf((float)(v1 - v0));   // in (0, 1]
            const float w1 = ex / (1.0f + ex);
            const float w0 = 1.0f - w1;

            if (lane == 0) {
                *reinterpret_cast<float2*>(&out[2 * (size_t)t]) =
                    make_float2((float)i0, (float)i1);
                *reinterpret_cast<float2*>(
                    &out[2 * (size_t)B_TOKENS + 2 * (size_t)t]) =
                    make_float2(w0, w1);
            }
        }

        // rotate prefetch buffer
#pragma unroll
        for (int g = 0; g < 3; ++g) buf[g] = nbuf[g];
    }
}

extern "C" void kernel_launch(void* const* d_in, const int* in_sizes, int n_in,
                              void* d_out, int out_size, void* d_ws, size_t ws_size,
                              hipStream_t stream) {
    const float* h  = (const float*)d_in[0];
    const float* gw = (const float*)d_in[1];
    const float* gb = (const float*)d_in[2];
    float* out = (float*)d_out;

    dim3 grid(2048), block(256);
    topic_router_kernel<<<grid, block, 0, stream>>>(h, gw, gb, out);
}

// Round 7
// 121.810 us; speedup vs baseline: 6.4265x; 1.6674x over previous
//
#include <hip/hip_runtime.h>

// TopicRouter: logits = h @ gate_w^T + gate_b ; top-2 ; softmax over top-2.
// Outputs flat in d_out (float32): [0, 2B)   = topk indices as floats
//                                  [2B, 4B)  = softmax weights
//
// R7: f32 hot path + rare f64 repair.
// Evidence: R3 (96 DS/token, no prefetch) == R6 (36 DS/token, prefetch) ==
// 203 us -> bottleneck is the shared 805M f64 FMAs (~8 TF effective f64).
// Fix: dot + butterfly + top-3 in f32; if min(gap12, gap23) < TAU=1e-4
// (worst-case f32 path error ~3e-6, 30x margin), redo the token in f64
// (wave-uniform: post-gather logits are identical in every lane). Expected
// trigger rate ~1e-3 -> ~130 tokens/launch, negligible.
// Wave-per-token; lane owns dims {g*256 + lane*4 + j}; gate_w in 96 f32
// VGPRs/lane; split-butterfly reduce (xor32/16/8 exchange halves, xor4/2/1
// reduce, 8-wide gather) = 18 b32 DS ops/token; one-token-ahead prefetch.

#define B_TOKENS 131072
#define DM 768
#define NE 8
#define TAU 1e-4f

__global__ __launch_bounds__(256) void topic_router_kernel(
    const float* __restrict__ h,     // [B, 768]
    const float* __restrict__ gw,    // [8, 768]
    const float* __restrict__ gb,    // [8]
    float* __restrict__ out)         // [2B idx floats][2B weight floats]
{
    const int lane = threadIdx.x & 63;
    const int wid = (blockIdx.x * blockDim.x + threadIdx.x) >> 6;
    const int n_waves = (gridDim.x * blockDim.x) >> 6;

    // Cache gate_w fragments: wf[e][g][j] = gw[e][g*256 + lane*4 + j]
    float wf[NE][3][4];
#pragma unroll
    for (int e = 0; e < NE; ++e)
#pragma unroll
        for (int g = 0; g < 3; ++g) {
            const float4 v = *reinterpret_cast<const float4*>(
                &gw[e * DM + g * 256 + lane * 4]);
            wf[e][g][0] = v.x; wf[e][g][1] = v.y;
            wf[e][g][2] = v.z; wf[e][g][3] = v.w;
        }

    float biasf[NE];
#pragma unroll
    for (int e = 0; e < NE; ++e) biasf[e] = gb[e];

    const bool hi32 = (lane & 32) != 0;
    const bool hi16 = (lane & 16) != 0;
    const bool hi8  = (lane & 8)  != 0;

    int t = wid;
    float4 buf[3];
    if (t < B_TOKENS) {
        const float* hr = h + (size_t)t * DM;
#pragma unroll
        for (int g = 0; g < 3; ++g)
            buf[g] = *reinterpret_cast<const float4*>(&hr[g * 256 + lane * 4]);
    }

    for (; t < B_TOKENS; t += n_waves) {
        // ---- prefetch next token's row ----
        float4 nbuf[3];
        const int tn = t + n_waves;
        if (tn < B_TOKENS) {
            const float* hr = h + (size_t)tn * DM;
#pragma unroll
            for (int g = 0; g < 3; ++g)
                nbuf[g] = *reinterpret_cast<const float4*>(&hr[g * 256 + lane * 4]);
        }

        // ---- f32 partial dot: 96 FMAs/lane ----
        float accf[NE] = {0, 0, 0, 0, 0, 0, 0, 0};
#pragma unroll
        for (int g = 0; g < 3; ++g) {
            const float* bp = reinterpret_cast<const float*>(&buf[g]);
#pragma unroll
            for (int j = 0; j < 4; ++j) {
                const float hv = bp[j];
#pragma unroll
                for (int e = 0; e < NE; ++e)
                    accf[e] = fmaf(hv, wf[e][g][j], accf[e]);
            }
        }

        // ---- f32 split-butterfly reduce (18 b32 DS ops) ----
        float r4[4];
#pragma unroll
        for (int j = 0; j < 4; ++j) {
            const float give = hi32 ? accf[j] : accf[4 + j];
            const float keep = hi32 ? accf[4 + j] : accf[j];
            r4[j] = keep + __shfl_xor(give, 32);
        }
        float r2[2];
#pragma unroll
        for (int j = 0; j < 2; ++j) {
            const float give = hi16 ? r4[j] : r4[2 + j];
            const float keep = hi16 ? r4[2 + j] : r4[j];
            r2[j] = keep + __shfl_xor(give, 16);
        }
        {
            const float give = hi8 ? r2[0] : r2[1];
            const float keep = hi8 ? r2[1] : r2[0];
            float v = keep + __shfl_xor(give, 8);
            v += __shfl_xor(v, 4);
            v += __shfl_xor(v, 2);
            v += __shfl_xor(v, 1);

            // gather all 8 logits into every lane (identical in all lanes)
            float lg[NE];
#pragma unroll
            for (int e = 0; e < NE; ++e)
                lg[e] = __shfl(v, (e << 3) | (lane & 7)) + biasf[e];

            // ---- f32 top-3 (lax.top_k tie-break: lower index wins) ----
            int i0 = 0; float v0 = lg[0];
#pragma unroll
            for (int e = 1; e < NE; ++e)
                if (lg[e] > v0) { v0 = lg[e]; i0 = e; }
            int i1 = -1; float v1 = -3.4e38f;
#pragma unroll
            for (int e = 0; e < NE; ++e)
                if (e != i0 && lg[e] > v1) { v1 = lg[e]; i1 = e; }
            float v2 = -3.4e38f;
#pragma unroll
            for (int e = 0; e < NE; ++e)
                if (e != i0 && e != i1 && lg[e] > v2) v2 = lg[e];

            float diff = v1 - v0;   // <= 0

            // ---- rare f64 repair when ranking is ambiguous in f32 ----
            if (__builtin_expect((v0 - v1 < TAU) || (v1 - v2 < TAU), 0)) {
                double acc[NE] = {0, 0, 0, 0, 0, 0, 0, 0};
#pragma unroll
                for (int g = 0; g < 3; ++g) {
                    const float* bp = reinterpret_cast<const float*>(&buf[g]);
#pragma unroll
                    for (int j = 0; j < 4; ++j) {
                        const double hd = (double)bp[j];
#pragma unroll
                        for (int e = 0; e < NE; ++e)
                            acc[e] = fma(hd, (double)wf[e][g][j], acc[e]);
                    }
                }
                double d4[4];
#pragma unroll
                for (int j = 0; j < 4; ++j) {
                    const double give = hi32 ? acc[j] : acc[4 + j];
                    const double keep = hi32 ? acc[4 + j] : acc[j];
                    d4[j] = keep + __shfl_xor(give, 32);
                }
                double d2[2];
#pragma unroll
                for (int j = 0; j < 2; ++j) {
                    const double give = hi16 ? d4[j] : d4[2 + j];
                    const double keep = hi16 ? d4[2 + j] : d4[j];
                    d2[j] = keep + __shfl_xor(give, 16);
                }
                const double give = hi8 ? d2[0] : d2[1];
                const double keep = hi8 ? d2[1] : d2[0];
                double dv = keep + __shfl_xor(give, 8);
                dv += __shfl_xor(dv, 4);
                dv += __shfl_xor(dv, 2);
                dv += __shfl_xor(dv, 1);

                double dlg[NE];
#pragma unroll
                for (int e = 0; e < NE; ++e)
                    dlg[e] = __shfl(dv, (e << 3) | (lane & 7)) +
                             (double)biasf[e];

                i0 = 0; double dv0 = dlg[0];
#pragma unroll
                for (int e = 1; e < NE; ++e)
                    if (dlg[e] > dv0) { dv0 = dlg[e]; i0 = e; }
                i1 = (i0 == 0) ? 1 : 0; double dv1 = dlg[i1];
#pragma unroll
                for (int e = 0; e < NE; ++e)
                    if (e != i0 && dlg[e] > dv1) { dv1 = dlg[e]; i1 = e; }
                diff = (float)(dv1 - dv0);
            }

            // softmax over top-2 (diff = logit1 - logit0 <= 0)
            const float ex = expf(diff);
            const float w1 = ex / (1.0f + ex);
            const float w0 = 1.0f - w1;

            if (lane == 0) {
                *reinterpret_cast<float2*>(&out[2 * (size_t)t]) =
                    make_float2((float)i0, (float)i1);
                *reinterpret_cast<float2*>(
                    &out[2 * (size_t)B_TOKENS + 2 * (size_t)t]) =
                    make_float2(w0, w1);
            }
        }

        // rotate prefetch buffer
#pragma unroll
        for (int g = 0; g < 3; ++g) buf[g] = nbuf[g];
    }
}

extern "C" void kernel_launch(void* const* d_in, const int* in_sizes, int n_in,
                              void* d_out, int out_size, void* d_ws, size_t ws_size,
                              hipStream_t stream) {
    const float* h  = (const float*)d_in[0];
    const float* gw = (const float*)d_in[1];
    const float* gb = (const float*)d_in[2];
    float* out = (float*)d_out;

    dim3 grid(2048), block(256);
    topic_router_kernel<<<grid, block, 0, stream>>>(h, gw, gb, out);
}